// Round 4
// baseline (1694.626 us; speedup 1.0000x reference)
//
#include <hip/hip_runtime.h>

// MultiHeadSelfAttention: B=4 T=1024 H=8 D=64 N_UNITS=512, fp32 in/out.
// R7: INSTRUMENTATION ROUND (deliberate dur regression; math identical to R6's
// 527.7us kernel). Grid-z amplification: qkv x8, flash x8, proj x24 inside
// single dispatches; z>0 replicas read real inputs, write scratch; z=0 writes
// real outputs. Amplified dispatches exceed the 160us fill threshold so the
// top-5 table finally shows OUR kernels' counters. pos_gemm kept x1 (256MB
// stream would be L3-distorted by replication) -> recovered by subtraction:
//   t_pos + t_prep + launches = dur - 320 - amp_qkv - amp_flash - amp_proj.
// flash VGPR (~200, launch_bounds(256,2)) pins amplified occupancy to the
// real 2-3 blocks/CU, so amp_flash/8 = t_flash in-regime.
// Fragment layouts (16x16x32_bf16): A/B = 8 contig k at row lane&15,
// k-offset (lane>>4)*8 ; C/D: col=lane&15, row=(lane>>4)*4+reg.

#define TT 1024
#define DH 64
#define NH 8
#define NU 512

typedef __bf16 bf16;
typedef bf16 bf16x8 __attribute__((ext_vector_type(8)));
typedef bf16 bf16x4 __attribute__((ext_vector_type(4)));
typedef float f32x4 __attribute__((ext_vector_type(4)));

#define MFMA16(a, b, c) __builtin_amdgcn_mfma_f32_16x16x32_bf16(a, b, c, 0, 0, 0)

// ---------------- prep: x -> bf16 + weights -> bf16 transposed [w][n][k] ----------------
__global__ __launch_bounds__(256) void prep_k(const float* __restrict__ x,
                                              const float* __restrict__ Wq,
                                              const float* __restrict__ Wk,
                                              const float* __restrict__ Wv,
                                              const float* __restrict__ Wo,
                                              bf16* __restrict__ xb,
                                              bf16* __restrict__ wt) {
  int bid = blockIdx.x, tid = threadIdx.x;
  {
    int i = bid * 256 + tid;
    float4 v = ((const float4*)x)[i];
    bf16x4 o = {(bf16)v.x, (bf16)v.y, (bf16)v.z, (bf16)v.w};
    ((bf16x4*)xb)[i] = o;
  }
  if ((bid & 3) == 0) {
    int u = bid >> 2;
    int w = u >> 7, rem = u & 127;
    int k0 = (rem >> 1) * 8;
    int n = (rem & 1) * 256 + tid;
    const float* W = (w == 0) ? Wq : (w == 1) ? Wk : (w == 2) ? Wv : Wo;
    bf16x8 v;
#pragma unroll
    for (int j = 0; j < 8; j++) v[j] = (bf16)W[(size_t)(k0 + j) * NU + n];
    *(bf16x8*)(wt + ((size_t)w * NU + n) * NU + k0) = v;
  }
}

// ---------------- fused QKV projection GEMM (64x64 tile, grid 8x64xZ) ----------------
__global__ __launch_bounds__(256) void qkv_k(
    const bf16* __restrict__ xb, const bf16* __restrict__ wt,
    const float* __restrict__ bq, const float* __restrict__ bk,
    const float* __restrict__ bv, bf16* __restrict__ Qb, bf16* __restrict__ Kb,
    bf16* __restrict__ Vt, bf16* __restrict__ sQb, bf16* __restrict__ sKb,
    bf16* __restrict__ sVt) {
  int tid = threadIdx.x, wid = tid >> 6, ln = tid & 63;
  int n15 = ln & 15, qd = ln >> 4;
  int n0 = blockIdx.x * 64, m0 = blockIdx.y * 64;
  int mrow = m0 + wid * 16 + n15;
  // z>0 replicas: identical work, scratch outputs (benign same-value races).
  bf16* Qo = blockIdx.z ? sQb : Qb;
  bf16* Ko = blockIdx.z ? sKb : Kb;
  bf16* Vo = blockIdx.z ? sVt : Vt;

  const f32x4 fz = {0.f, 0.f, 0.f, 0.f};
  f32x4 acc[3][4];
#pragma unroll
  for (int w = 0; w < 3; w++)
#pragma unroll
    for (int nt = 0; nt < 4; nt++) acc[w][nt] = fz;

  for (int k0 = 0; k0 < NU; k0 += 32) {
    bf16x8 a = *(const bf16x8*)(xb + (size_t)mrow * NU + k0 + qd * 8);
#pragma unroll
    for (int w = 0; w < 3; w++)
#pragma unroll
      for (int nt = 0; nt < 4; nt++) {
        bf16x8 b = *(const bf16x8*)(wt + ((size_t)w * NU + n0 + nt * 16 + n15) * NU +
                                    k0 + qd * 8);
        acc[w][nt] = MFMA16(a, b, acc[w][nt]);
      }
  }

  int bb = m0 >> 10;
  int tbase = (m0 & 1023) + wid * 16 + qd * 4;
  int hh = n0 >> 6;
#pragma unroll
  for (int nt = 0; nt < 4; nt++) {
    int d = nt * 16 + n15;
    float bqv = bq[n0 + d], bkv = bk[n0 + d], bvv = bv[n0 + d];
    bf16x4 vv;
#pragma unroll
    for (int r = 0; r < 4; r++) {
      int t = tbase + r;
      size_t qk_idx = ((size_t)(bb * NH + hh) * TT + t) * DH + d;
      Qo[qk_idx] = (bf16)(acc[0][nt][r] + bqv);
      Ko[qk_idx] = (bf16)(acc[1][nt][r] + bkv);
      vv[r] = (bf16)(acc[2][nt][r] + bvv);
    }
    *(bf16x4*)(Vo + ((size_t)(bb * NH + hh) * DH + d) * TT + tbase) = vv;
  }
}

// ---------------- pos-score GEMM (transposed: M=s, N=bh) — unchanged, x1 ----------------
__global__ __launch_bounds__(256) void pos_gemm_k(const float* __restrict__ pos,
                                                  const bf16* __restrict__ Qb,
                                                  bf16* __restrict__ biasF) {
  int tid = threadIdx.x, wid = tid >> 6, ln = tid & 63;
  int n15 = ln & 15, qd = ln >> 4;
  int t = blockIdx.y;
  int s0b = blockIdx.x * 128;

  __shared__ bf16 Qs[32 * 72];
  {
    int bh = tid >> 3, dc = (tid & 7) * 8;
    *(bf16x8*)(&Qs[bh * 72 + dc]) =
        *(const bf16x8*)(Qb + ((size_t)bh * TT + t) * DH + dc);
  }
  __syncthreads();

  bf16x8 bQ[2][2];
#pragma unroll
  for (int bht = 0; bht < 2; bht++)
#pragma unroll
    for (int kc = 0; kc < 2; kc++)
      bQ[bht][kc] = *(const bf16x8*)(&Qs[(bht * 16 + n15) * 72 + kc * 32 + qd * 8]);

  const f32x4 fz = {0.f, 0.f, 0.f, 0.f};
  f32x4 acc[2][2];
#pragma unroll
  for (int stl = 0; stl < 2; stl++)
#pragma unroll
    for (int bht = 0; bht < 2; bht++) acc[stl][bht] = fz;

  int sw = s0b + wid * 32;
#pragma unroll
  for (int stl = 0; stl < 2; stl++) {
    const float* pr = pos + ((size_t)t * TT + sw + stl * 16 + n15) * DH + qd * 8;
#pragma unroll
    for (int kc = 0; kc < 2; kc++) {
      f32x4 u = __builtin_nontemporal_load((const f32x4*)(pr + kc * 32));
      f32x4 v = __builtin_nontemporal_load((const f32x4*)(pr + kc * 32 + 4));
      bf16x8 aP = {(bf16)u[0], (bf16)u[1], (bf16)u[2], (bf16)u[3],
                   (bf16)v[0], (bf16)v[1], (bf16)v[2], (bf16)v[3]};
#pragma unroll
      for (int bht = 0; bht < 2; bht++)
        acc[stl][bht] = MFMA16(aP, bQ[bht][kc], acc[stl][bht]);
    }
  }

  int t16 = t >> 4, tin = t & 15, s32 = (s0b >> 5) + wid;
#pragma unroll
  for (int bht = 0; bht < 2; bht++) {
    bf16x8 ov;
#pragma unroll
    for (int r = 0; r < 4; r++) {
      ov[r] = (bf16)acc[0][bht][r];
      ov[4 + r] = (bf16)acc[1][bht][r];
    }
    *(bf16x8*)(biasF +
               (((size_t)(bht * 16 + n15) * 64 + t16) * 32 + s32) * 512 +
               tin * 32 + qd * 8) = ov;
  }
}

// ---------------- flash attention (R6 s-step-64 form, grid 32x16xZ) ----------------
__global__ __launch_bounds__(256, 2) void flash_k(const bf16* __restrict__ Qb,
                                                  const bf16* __restrict__ Kb,
                                                  const bf16* __restrict__ Vt,
                                                  const bf16* __restrict__ biasF,
                                                  bf16* __restrict__ att,
                                                  bf16* __restrict__ sAtt) {
  int tid = threadIdx.x, wid = tid >> 6, ln = tid & 63;
  int n15 = ln & 15, qd = ln >> 4;
  int bh = blockIdx.x;
  int t0 = blockIdx.y * 64 + wid * 16;
  bf16* ao = blockIdx.z ? sAtt : att;
  const float SC = 0.18033688f;  // log2(e)/8

  __shared__ bf16 Pl[4][16][72];

  bf16x8 bQ[2];
#pragma unroll
  for (int kc = 0; kc < 2; kc++)
    bQ[kc] = *(const bf16x8*)(Qb + ((size_t)bh * TT + t0 + n15) * DH + kc * 32 + qd * 8);

  const bf16* Kbase = Kb + (size_t)bh * TT * DH;
  const bf16* Vbase = Vt + (size_t)bh * DH * TT;
  const bf16* Fbase = biasF + (((size_t)bh * 64 + (t0 >> 4)) * 32) * 512 +
                      n15 * 32 + qd * 8;

  const f32x4 fz = {0.f, 0.f, 0.f, 0.f};
  f32x4 accO[4] = {fz, fz, fz, fz};
  f32x4 accL = fz;
  const bf16 one = (bf16)1.0f;
  const bf16x8 onesv = {one, one, one, one, one, one, one, one};

  bf16x8 Kf[2][8], Vf[2][8];
  bf16x8 Bf[2][2];

  auto ldKV = [&](int buf, int s0) {
#pragma unroll
    for (int mt = 0; mt < 4; mt++)
#pragma unroll
      for (int kc = 0; kc < 2; kc++)
        Kf[buf][mt * 2 + kc] =
            *(const bf16x8*)(Kbase + (size_t)(s0 + mt * 16 + n15) * DH + kc * 32 + qd * 8);
#pragma unroll
    for (int dt = 0; dt < 4; dt++)
#pragma unroll
      for (int sc = 0; sc < 2; sc++)
        Vf[buf][dt * 2 + sc] =
            *(const bf16x8*)(Vbase + (size_t)(dt * 16 + n15) * TT + s0 + sc * 32 + qd * 8);
  };
  auto ldB = [&](int buf, int s0) {
#pragma unroll
    for (int sc = 0; sc < 2; sc++)
      Bf[buf][sc] = *(const bf16x8*)(Fbase + (size_t)((s0 >> 5) + sc) * 512);
  };

  ldKV(0, 0);
  ldB(0, 0);

#pragma unroll 2
  for (int it = 0; it < 16; it++) {
    int s0 = it * 64;
    int cb = it & 1, nb = (it + 1) & 1;
    ldKV(nb, (s0 + 64) & 1023);
    ldB(nb, (s0 + 64) & 1023);

    f32x4 accS[4] = {fz, fz, fz, fz};
#pragma unroll
    for (int mt = 0; mt < 4; mt++)
#pragma unroll
      for (int kc = 0; kc < 2; kc++)
        accS[mt] = MFMA16(Kf[cb][mt * 2 + kc], bQ[kc], accS[mt]);

#pragma unroll
    for (int mt = 0; mt < 4; mt++) {
      bf16x4 pb;
#pragma unroll
      for (int r = 0; r < 4; r++) {
        float p = __builtin_amdgcn_exp2f(
            (accS[mt][r] + (float)Bf[cb][mt >> 1][(mt & 1) * 4 + r]) * SC);
        pb[r] = (bf16)p;
      }
      *(bf16x4*)(&Pl[wid][n15][mt * 16 + qd * 4]) = pb;
    }

#pragma unroll
    for (int sc = 0; sc < 2; sc++) {
      bf16x8 bP = *(const bf16x8*)(&Pl[wid][n15][sc * 32 + qd * 8]);
      accL = MFMA16(onesv, bP, accL);
#pragma unroll
      for (int dt = 0; dt < 4; dt++)
        accO[dt] = MFMA16(Vf[cb][dt * 2 + sc], bP, accO[dt]);
    }
  }

  int bb = bh >> 3, hh = bh & 7;
  float rcp = 1.0f / accL[0];
#pragma unroll
  for (int dt = 0; dt < 4; dt++) {
    bf16x4 ov;
#pragma unroll
    for (int r = 0; r < 4; r++) ov[r] = (bf16)(accO[dt][r] * rcp);
    *(bf16x4*)(ao + ((size_t)bb * TT + t0 + n15) * NU + hh * DH + dt * 16 + qd * 4) = ov;
  }
}

// ---------------- output projection (64x64 tile, grid 8x64xZ) ----------------
__global__ __launch_bounds__(256) void proj_k(const bf16* __restrict__ att,
                                              const bf16* __restrict__ wt,
                                              const float* __restrict__ bo,
                                              float* __restrict__ out,
                                              float* __restrict__ sOut) {
  int tid = threadIdx.x, wid = tid >> 6, ln = tid & 63;
  int n15 = ln & 15, qd = ln >> 4;
  int n0 = blockIdx.x * 64, m0 = blockIdx.y * 64;
  int mrow = m0 + wid * 16 + n15;
  float* op = blockIdx.z ? sOut : out;

  const f32x4 fz = {0.f, 0.f, 0.f, 0.f};
  f32x4 acc[4] = {fz, fz, fz, fz};
  for (int k0 = 0; k0 < NU; k0 += 32) {
    bf16x8 a = *(const bf16x8*)(att + (size_t)mrow * NU + k0 + qd * 8);
#pragma unroll
    for (int nt = 0; nt < 4; nt++) {
      bf16x8 b = *(const bf16x8*)(wt + ((size_t)3 * NU + n0 + nt * 16 + n15) * NU +
                                  k0 + qd * 8);
      acc[nt] = MFMA16(a, b, acc[nt]);
    }
  }
#pragma unroll
  for (int nt = 0; nt < 4; nt++) {
    int col = n0 + nt * 16 + n15;
    float bov = bo[col];
#pragma unroll
    for (int r = 0; r < 4; r++) {
      int row = m0 + wid * 16 + qd * 4 + r;
      op[(size_t)row * NU + col] = acc[nt][r] + bov;
    }
  }
}

extern "C" void kernel_launch(void* const* d_in, const int* in_sizes, int n_in,
                              void* d_out, int out_size, void* d_ws, size_t ws_size,
                              hipStream_t stream) {
  const float* x = (const float*)d_in[0];
  const float* pos = (const float*)d_in[1];
  const float* Wq = (const float*)d_in[3];
  const float* bq = (const float*)d_in[4];
  const float* Wk = (const float*)d_in[5];
  const float* bk = (const float*)d_in[6];
  const float* Wv = (const float*)d_in[7];
  const float* bv = (const float*)d_in[8];
  const float* Wo = (const float*)d_in[9];
  const float* bo = (const float*)d_in[10];
  float* out = (float*)d_out;

  char* ws = (char*)d_ws;
  bf16* xb = (bf16*)(ws);                          // 4 MB
  bf16* wt = (bf16*)(ws + ((size_t)4 << 20));      // 2 MB  [4][512][512]
  bf16* Qb = (bf16*)(ws + ((size_t)6 << 20));      // 4 MB  [bh][t][d]
  bf16* Kb = (bf16*)(ws + ((size_t)10 << 20));     // 4 MB  [bh][t][d]
  bf16* Vt = (bf16*)(ws + ((size_t)14 << 20));     // 4 MB  [bh][d][t]
  bf16* att = (bf16*)(ws + ((size_t)18 << 20));    // 4 MB  [row][unit]
  bf16* biasF = (bf16*)(ws + ((size_t)22 << 20));  // 64 MB frag-packed tiles
  // replica scratch (same-value benign races among z>0 replicas)
  bf16* sQb = (bf16*)(ws + ((size_t)128 << 20));   // 4 MB
  bf16* sKb = (bf16*)(ws + ((size_t)132 << 20));   // 4 MB
  bf16* sVt = (bf16*)(ws + ((size_t)136 << 20));   // 4 MB
  bf16* sAtt = (bf16*)(ws + ((size_t)140 << 20));  // 4 MB
  float* sOut = (float*)(ws + ((size_t)144 << 20));  // 8 MB

  prep_k<<<2048, 256, 0, stream>>>(x, Wq, Wk, Wv, Wo, xb, wt);
  qkv_k<<<dim3(8, 64, 8), 256, 0, stream>>>(xb, wt, bq, bk, bv, Qb, Kb, Vt,
                                            sQb, sKb, sVt);
  pos_gemm_k<<<dim3(8, 1024), 256, 0, stream>>>(pos, Qb, biasF);
  flash_k<<<dim3(32, 16, 8), 256, 0, stream>>>(Qb, Kb, Vt, biasF, att, sAtt);
  proj_k<<<dim3(8, 64, 24), 256, 0, stream>>>(att, wt, bo, out, sOut);
}

// Round 5
// 529.934 us; speedup vs baseline: 3.1978x; 3.1978x over previous
//
#include <hip/hip_runtime.h>

// MultiHeadSelfAttention: B=4 T=1024 H=8 D=64 N_UNITS=512, fp32 in/out.
// R8: SCRATCH FIX in flash. R7 amplification showed flash = 67us/replica with
// VGPR_Count=72 despite ~144 VGPR of declared fragments -> Kf[2][8]/Vf[2][8]
// runtime-indexed by it&1 went to SCRATCH (rule: runtime-indexed ext_vector
// arrays -> local memory). Every iter round-tripped ~1KB/lane through scratch:
// that's the 10K-cycle iterations, 5.9% MfmaUtil, and why R3==R6 to 0.04us
// (both scratch-bound). Fix: named A/B buffers (KfA/KfB/...), all indices
// compile-time via fully-unrolled loops, 8 x (ldB|computeA|ldA'|computeB)
// dist-1 pipeline. ~205 VGPR static, launch_bounds(256,2), 2 blocks/CU.
// Everything else = verified 527.7us pipeline (single-variable change).
// Attribution (R7): flash 67, pos ~55, qkv ~45, proj ~20, prep+launch ~20,
// plus ~320us fixed in-window harness poison fills.
// Fragment layouts (16x16x32_bf16): A/B = 8 contig k at row lane&15,
// k-offset (lane>>4)*8 ; C/D: col=lane&15, row=(lane>>4)*4+reg.

#define TT 1024
#define DH 64
#define NH 8
#define NU 512

typedef __bf16 bf16;
typedef bf16 bf16x8 __attribute__((ext_vector_type(8)));
typedef bf16 bf16x4 __attribute__((ext_vector_type(4)));
typedef float f32x4 __attribute__((ext_vector_type(4)));

#define MFMA16(a, b, c) __builtin_amdgcn_mfma_f32_16x16x32_bf16(a, b, c, 0, 0, 0)

// ---------------- prep: x -> bf16 + weights -> bf16 transposed [w][n][k] ----------------
__global__ __launch_bounds__(256) void prep_k(const float* __restrict__ x,
                                              const float* __restrict__ Wq,
                                              const float* __restrict__ Wk,
                                              const float* __restrict__ Wv,
                                              const float* __restrict__ Wo,
                                              bf16* __restrict__ xb,
                                              bf16* __restrict__ wt) {
  int bid = blockIdx.x, tid = threadIdx.x;
  {
    int i = bid * 256 + tid;
    float4 v = ((const float4*)x)[i];
    bf16x4 o = {(bf16)v.x, (bf16)v.y, (bf16)v.z, (bf16)v.w};
    ((bf16x4*)xb)[i] = o;
  }
  if ((bid & 3) == 0) {
    int u = bid >> 2;
    int w = u >> 7, rem = u & 127;
    int k0 = (rem >> 1) * 8;
    int n = (rem & 1) * 256 + tid;
    const float* W = (w == 0) ? Wq : (w == 1) ? Wk : (w == 2) ? Wv : Wo;
    bf16x8 v;
#pragma unroll
    for (int j = 0; j < 8; j++) v[j] = (bf16)W[(size_t)(k0 + j) * NU + n];
    *(bf16x8*)(wt + ((size_t)w * NU + n) * NU + k0) = v;
  }
}

// ---------------- fused QKV projection GEMM (64x64 tile, grid 8x64) ----------------
__global__ __launch_bounds__(256) void qkv_k(
    const bf16* __restrict__ xb, const bf16* __restrict__ wt,
    const float* __restrict__ bq, const float* __restrict__ bk,
    const float* __restrict__ bv, bf16* __restrict__ Qb, bf16* __restrict__ Kb,
    bf16* __restrict__ Vt) {
  int tid = threadIdx.x, wid = tid >> 6, ln = tid & 63;
  int n15 = ln & 15, qd = ln >> 4;
  int n0 = blockIdx.x * 64, m0 = blockIdx.y * 64;
  int mrow = m0 + wid * 16 + n15;

  const f32x4 fz = {0.f, 0.f, 0.f, 0.f};
  f32x4 acc[3][4];
#pragma unroll
  for (int w = 0; w < 3; w++)
#pragma unroll
    for (int nt = 0; nt < 4; nt++) acc[w][nt] = fz;

  for (int k0 = 0; k0 < NU; k0 += 32) {
    bf16x8 a = *(const bf16x8*)(xb + (size_t)mrow * NU + k0 + qd * 8);
#pragma unroll
    for (int w = 0; w < 3; w++)
#pragma unroll
      for (int nt = 0; nt < 4; nt++) {
        bf16x8 b = *(const bf16x8*)(wt + ((size_t)w * NU + n0 + nt * 16 + n15) * NU +
                                    k0 + qd * 8);
        acc[w][nt] = MFMA16(a, b, acc[w][nt]);
      }
  }

  int bb = m0 >> 10;
  int tbase = (m0 & 1023) + wid * 16 + qd * 4;
  int hh = n0 >> 6;
#pragma unroll
  for (int nt = 0; nt < 4; nt++) {
    int d = nt * 16 + n15;
    float bqv = bq[n0 + d], bkv = bk[n0 + d], bvv = bv[n0 + d];
    bf16x4 vv;
#pragma unroll
    for (int r = 0; r < 4; r++) {
      int t = tbase + r;
      size_t qk_idx = ((size_t)(bb * NH + hh) * TT + t) * DH + d;
      Qb[qk_idx] = (bf16)(acc[0][nt][r] + bqv);
      Kb[qk_idx] = (bf16)(acc[1][nt][r] + bkv);
      vv[r] = (bf16)(acc[2][nt][r] + bvv);
    }
    *(bf16x4*)(Vt + ((size_t)(bb * NH + hh) * DH + d) * TT + tbase) = vv;
  }
}

// ---------------- pos-score GEMM (transposed: M=s, N=bh) — unchanged ----------------
// bias[bh][t][s] = Q[bh,t,:] . pos_k[t,s,:], stored fragment-packed:
// biasF tile (bh, t16=t/16, s32=s/32) = 512 elems; elem (tin, qd, mt, r) at
// tin*32 + qd*8 + mt*4 + r  ->  value bias[bh][t16*16+tin][s32*32+mt*16+qd*4+r]
__global__ __launch_bounds__(256) void pos_gemm_k(const float* __restrict__ pos,
                                                  const bf16* __restrict__ Qb,
                                                  bf16* __restrict__ biasF) {
  int tid = threadIdx.x, wid = tid >> 6, ln = tid & 63;
  int n15 = ln & 15, qd = ln >> 4;
  int t = blockIdx.y;
  int s0b = blockIdx.x * 128;

  __shared__ bf16 Qs[32 * 72];
  {
    int bh = tid >> 3, dc = (tid & 7) * 8;
    *(bf16x8*)(&Qs[bh * 72 + dc]) =
        *(const bf16x8*)(Qb + ((size_t)bh * TT + t) * DH + dc);
  }
  __syncthreads();

  bf16x8 bQ[2][2];
#pragma unroll
  for (int bht = 0; bht < 2; bht++)
#pragma unroll
    for (int kc = 0; kc < 2; kc++)
      bQ[bht][kc] = *(const bf16x8*)(&Qs[(bht * 16 + n15) * 72 + kc * 32 + qd * 8]);

  const f32x4 fz = {0.f, 0.f, 0.f, 0.f};
  f32x4 acc[2][2];
#pragma unroll
  for (int stl = 0; stl < 2; stl++)
#pragma unroll
    for (int bht = 0; bht < 2; bht++) acc[stl][bht] = fz;

  int sw = s0b + wid * 32;
#pragma unroll
  for (int stl = 0; stl < 2; stl++) {
    const float* pr = pos + ((size_t)t * TT + sw + stl * 16 + n15) * DH + qd * 8;
#pragma unroll
    for (int kc = 0; kc < 2; kc++) {
      f32x4 u = __builtin_nontemporal_load((const f32x4*)(pr + kc * 32));
      f32x4 v = __builtin_nontemporal_load((const f32x4*)(pr + kc * 32 + 4));
      bf16x8 aP = {(bf16)u[0], (bf16)u[1], (bf16)u[2], (bf16)u[3],
                   (bf16)v[0], (bf16)v[1], (bf16)v[2], (bf16)v[3]};
#pragma unroll
      for (int bht = 0; bht < 2; bht++)
        acc[stl][bht] = MFMA16(aP, bQ[bht][kc], acc[stl][bht]);
    }
  }

  int t16 = t >> 4, tin = t & 15, s32 = (s0b >> 5) + wid;
#pragma unroll
  for (int bht = 0; bht < 2; bht++) {
    bf16x8 ov;
#pragma unroll
    for (int r = 0; r < 4; r++) {
      ov[r] = (bf16)acc[0][bht][r];
      ov[4 + r] = (bf16)acc[1][bht][r];
    }
    *(bf16x8*)(biasF +
               (((size_t)(bht * 16 + n15) * 64 + t16) * 32 + s32) * 512 +
               tin * 32 + qd * 8) = ov;
  }
}

// ---------------- flash attention (S^T form, static-register dist-1 pipeline) ----------------
// grid (32 bh, 16 tb); 4 waves x 16 t. 8 iters x 128 s, two named 64-s
// register buffers (A/B) — NO runtime buffer index anywhere (scratch fix).
// Per 64-s compute: 18 MFMA, 16 exp, 4 ds_write_b64, 2 ds_read_b128.

#define FL_LD(SUF, s0)                                                          \
  {                                                                             \
    _Pragma("unroll") for (int mt = 0; mt < 4; mt++)                            \
        _Pragma("unroll") for (int kc = 0; kc < 2; kc++)                        \
            Kf##SUF[mt * 2 + kc] = *(const bf16x8*)(                            \
                Kbase + (size_t)((s0) + mt * 16 + n15) * DH + kc * 32 + qd * 8);\
    _Pragma("unroll") for (int dt = 0; dt < 4; dt++)                            \
        _Pragma("unroll") for (int sc = 0; sc < 2; sc++)                        \
            Vf##SUF[dt * 2 + sc] = *(const bf16x8*)(                            \
                Vbase + (size_t)(dt * 16 + n15) * TT + (s0) + sc * 32 + qd * 8);\
    _Pragma("unroll") for (int sc = 0; sc < 2; sc++)                            \
        Bf##SUF[sc] =                                                           \
            *(const bf16x8*)(Fbase + (size_t)(((s0) >> 5) + sc) * 512);         \
  }

#define FL_COMPUTE(SUF)                                                         \
  {                                                                             \
    f32x4 accS[4] = {fz, fz, fz, fz};                                           \
    _Pragma("unroll") for (int mt = 0; mt < 4; mt++)                            \
        _Pragma("unroll") for (int kc = 0; kc < 2; kc++)                        \
            accS[mt] = MFMA16(Kf##SUF[mt * 2 + kc], bQ[kc], accS[mt]);          \
    _Pragma("unroll") for (int mt = 0; mt < 4; mt++) {                          \
      bf16x4 pb;                                                                \
      _Pragma("unroll") for (int r = 0; r < 4; r++) {                           \
        float p = __builtin_amdgcn_exp2f(                                       \
            (accS[mt][r] + (float)Bf##SUF[mt >> 1][(mt & 1) * 4 + r]) * SC);    \
        pb[r] = (bf16)p;                                                        \
      }                                                                         \
      *(bf16x4*)(&Pl[wid][n15][mt * 16 + qd * 4]) = pb;                         \
    }                                                                           \
    _Pragma("unroll") for (int sc = 0; sc < 2; sc++) {                          \
      bf16x8 bP = *(const bf16x8*)(&Pl[wid][n15][sc * 32 + qd * 8]);            \
      accL = MFMA16(onesv, bP, accL);                                           \
      _Pragma("unroll") for (int dt = 0; dt < 4; dt++)                          \
          accO[dt] = MFMA16(Vf##SUF[dt * 2 + sc], bP, accO[dt]);                \
    }                                                                           \
  }

__global__ __launch_bounds__(256, 2) void flash_k(const bf16* __restrict__ Qb,
                                                  const bf16* __restrict__ Kb,
                                                  const bf16* __restrict__ Vt,
                                                  const bf16* __restrict__ biasF,
                                                  bf16* __restrict__ att) {
  int tid = threadIdx.x, wid = tid >> 6, ln = tid & 63;
  int n15 = ln & 15, qd = ln >> 4;
  int bh = blockIdx.x;
  int t0 = blockIdx.y * 64 + wid * 16;
  const float SC = 0.18033688f;  // log2(e)/8

  __shared__ bf16 Pl[4][16][72];  // per-wave P^T tile [t][s(64)+pad]

  // Q as B-operand: B[n=t][k=d]
  bf16x8 bQ[2];
#pragma unroll
  for (int kc = 0; kc < 2; kc++)
    bQ[kc] = *(const bf16x8*)(Qb + ((size_t)bh * TT + t0 + n15) * DH + kc * 32 + qd * 8);

  const bf16* Kbase = Kb + (size_t)bh * TT * DH;
  const bf16* Vbase = Vt + (size_t)bh * DH * TT;
  const bf16* Fbase = biasF + (((size_t)bh * 64 + (t0 >> 4)) * 32) * 512 +
                      n15 * 32 + qd * 8;  // + s32*512

  const f32x4 fz = {0.f, 0.f, 0.f, 0.f};
  f32x4 accO[4] = {fz, fz, fz, fz};
  f32x4 accL = fz;
  const bf16 one = (bf16)1.0f;
  const bf16x8 onesv = {one, one, one, one, one, one, one, one};

  // Named static buffers — every index below is compile-time (fully unrolled).
  bf16x8 KfA[8], VfA[8], BfA[2];
  bf16x8 KfB[8], VfB[8], BfB[2];

  FL_LD(A, 0)
  for (int it = 0; it < 8; it++) {
    int sA = it * 128;
    FL_LD(B, sA + 64)             // prefetch B while computing A
    FL_COMPUTE(A)
    FL_LD(A, (sA + 128) & 1023)   // prefetch next A (it=7: dead reload of s=0)
    FL_COMPUTE(B)
  }

  int bb = bh >> 3, hh = bh & 7;
  float rcp = 1.0f / accL[0];  // denom for t = t0+n15 (all rows identical)
#pragma unroll
  for (int dt = 0; dt < 4; dt++) {
    bf16x4 ov;
#pragma unroll
    for (int r = 0; r < 4; r++) ov[r] = (bf16)(accO[dt][r] * rcp);
    *(bf16x4*)(att + ((size_t)bb * TT + t0 + n15) * NU + hh * DH + dt * 16 + qd * 4) = ov;
  }
}

// ---------------- output projection (64x64 tile, grid 8x64) ----------------
__global__ __launch_bounds__(256) void proj_k(const bf16* __restrict__ att,
                                              const bf16* __restrict__ wt,
                                              const float* __restrict__ bo,
                                              float* __restrict__ out) {
  int tid = threadIdx.x, wid = tid >> 6, ln = tid & 63;
  int n15 = ln & 15, qd = ln >> 4;
  int n0 = blockIdx.x * 64, m0 = blockIdx.y * 64;
  int mrow = m0 + wid * 16 + n15;

  const f32x4 fz = {0.f, 0.f, 0.f, 0.f};
  f32x4 acc[4] = {fz, fz, fz, fz};
  for (int k0 = 0; k0 < NU; k0 += 32) {
    bf16x8 a = *(const bf16x8*)(att + (size_t)mrow * NU + k0 + qd * 8);
#pragma unroll
    for (int nt = 0; nt < 4; nt++) {
      bf16x8 b = *(const bf16x8*)(wt + ((size_t)3 * NU + n0 + nt * 16 + n15) * NU +
                                  k0 + qd * 8);
      acc[nt] = MFMA16(a, b, acc[nt]);
    }
  }
#pragma unroll
  for (int nt = 0; nt < 4; nt++) {
    int col = n0 + nt * 16 + n15;
    float bov = bo[col];
#pragma unroll
    for (int r = 0; r < 4; r++) {
      int row = m0 + wid * 16 + qd * 4 + r;
      out[(size_t)row * NU + col] = acc[nt][r] + bov;
    }
  }
}

extern "C" void kernel_launch(void* const* d_in, const int* in_sizes, int n_in,
                              void* d_out, int out_size, void* d_ws, size_t ws_size,
                              hipStream_t stream) {
  const float* x = (const float*)d_in[0];
  const float* pos = (const float*)d_in[1];
  const float* Wq = (const float*)d_in[3];
  const float* bq = (const float*)d_in[4];
  const float* Wk = (const float*)d_in[5];
  const float* bk = (const float*)d_in[6];
  const float* Wv = (const float*)d_in[7];
  const float* bv = (const float*)d_in[8];
  const float* Wo = (const float*)d_in[9];
  const float* bo = (const float*)d_in[10];
  float* out = (float*)d_out;

  char* ws = (char*)d_ws;
  bf16* xb = (bf16*)(ws);                          // 4 MB
  bf16* wt = (bf16*)(ws + ((size_t)4 << 20));      // 2 MB  [4][512][512]
  bf16* Qb = (bf16*)(ws + ((size_t)6 << 20));      // 4 MB  [bh][t][d]
  bf16* Kb = (bf16*)(ws + ((size_t)10 << 20));     // 4 MB  [bh][t][d]
  bf16* Vt = (bf16*)(ws + ((size_t)14 << 20));     // 4 MB  [bh][d][t]
  bf16* att = (bf16*)(ws + ((size_t)18 << 20));    // 4 MB  [row][unit]
  bf16* biasF = (bf16*)(ws + ((size_t)22 << 20));  // 64 MB frag-packed tiles

  prep_k<<<2048, 256, 0, stream>>>(x, Wq, Wk, Wv, Wo, xb, wt);
  qkv_k<<<dim3(8, 64), 256, 0, stream>>>(xb, wt, bq, bk, bv, Qb, Kb, Vt);
  pos_gemm_k<<<dim3(8, 1024), 256, 0, stream>>>(pos, Qb, biasF);
  flash_k<<<dim3(32, 16), 256, 0, stream>>>(Qb, Kb, Vt, biasF, att);
  proj_k<<<dim3(8, 64), 256, 0, stream>>>(att, wt, bo, out);
}